// Round 1
// baseline (706.799 us; speedup 1.0000x reference)
//
#include <hip/hip_runtime.h>

#define T_STEPS 256
#define H1 5
#define H2 100

// tanh(x) = 1 - 2/(exp(2x)+1); saturates correctly for |x| large.
__device__ __forceinline__ float fast_tanh(float v) {
    float e = __expf(2.0f * v);
    return 1.0f - 2.0f * __builtin_amdgcn_rcpf(e + 1.0f);
}

// One block per batch element. 128 threads = 2 waves.
// lane j (< 100): owns output component j of layer-2 hidden state.
//   - Whh2 row j and Wih2 row j live in registers (fully unrolled static indexing).
//   - shared h2 state double-buffered in LDS; read as uniform float4 broadcasts.
// lanes 64..68: additionally run the 5-dim layer-1 recurrence one step ahead.
__global__ __launch_bounds__(128) void rnn_fused(
    const float* __restrict__ x,
    const float* __restrict__ Wih1, const float* __restrict__ Whh1,
    const float* __restrict__ bih1, const float* __restrict__ bhh1,
    const float* __restrict__ Wih2, const float* __restrict__ Whh2,
    const float* __restrict__ bih2, const float* __restrict__ bhh2,
    const float* __restrict__ W3,   const float* __restrict__ b3,
    float* __restrict__ out)
{
    const int b   = blockIdx.x;
    const int tid = threadIdx.x;            // 0..127
    const int j   = tid;
    const bool jact = (j < H2);
    const int jj  = jact ? j : 0;

    __shared__ __align__(16) float h2s[2][104];  // padded, float4-aligned rows
    __shared__ __align__(16) float h1s[2][8];

    // ---- per-lane layer-2 weight row (registers) ----
    float w2[H2];
    #pragma unroll
    for (int k4 = 0; k4 < H2 / 4; ++k4) {
        float4 v = *reinterpret_cast<const float4*>(Whh2 + jj * H2 + 4 * k4);
        w2[4 * k4 + 0] = v.x; w2[4 * k4 + 1] = v.y;
        w2[4 * k4 + 2] = v.z; w2[4 * k4 + 3] = v.w;
    }
    float wi2[H1];
    #pragma unroll
    for (int k = 0; k < H1; ++k) wi2[k] = Wih2[jj * H1 + k];
    const float bias2 = bih2[jj] + bhh2[jj];

    // ---- layer-1 lanes (tid 64..68) ----
    const int  l1i   = tid - 64;
    const bool l1act = (l1i >= 0) && (l1i < H1);
    const int  li    = l1act ? l1i : 0;
    float w1[H1];
    #pragma unroll
    for (int k = 0; k < H1; ++k) w1[k] = Whh1[li * H1 + k];
    const float wi1 = Wih1[li];
    const float b1  = bih1[li] + bhh1[li];

    // ---- init state ----
    if (tid < 104) { h2s[0][tid] = 0.0f; h2s[1][tid] = 0.0f; }
    if (tid < 8)   { h1s[0][tid] = 0.0f; h1s[1][tid] = 0.0f; }
    __syncthreads();
    if (l1act) {  // h1[0] = tanh(Wih1*x0 + bih1 + bhh1)   (h1_{-1} = 0)
        float u = wi1 * x[b * T_STEPS + 0] + b1;
        h1s[0][li] = fast_tanh(u);
    }
    __syncthreads();

    // ---- main recurrence ----
    int cur = 0;
    float hn = 0.0f;
    for (int t = 0; t < T_STEPS; ++t) {
        const int nxt = cur ^ 1;

        // layer-2: s_j = bias + Wih2[j,:]·h1[t] + Whh2[j,:]·h2[t-1]
        float s0 = bias2, s1 = 0.0f, s2 = 0.0f, s3 = 0.0f;
        #pragma unroll
        for (int k = 0; k < H1; ++k) s1 += wi2[k] * h1s[cur][k];
        #pragma unroll
        for (int k4 = 0; k4 < H2 / 4; ++k4) {
            const float4 hv = *reinterpret_cast<const float4*>(&h2s[cur][4 * k4]);
            s0 += w2[4 * k4 + 0] * hv.x;
            s1 += w2[4 * k4 + 1] * hv.y;
            s2 += w2[4 * k4 + 2] * hv.z;
            s3 += w2[4 * k4 + 3] * hv.w;
        }
        hn = fast_tanh((s0 + s1) + (s2 + s3));

        // layer-1: compute h1[t+1] while others do the big matvec
        const bool dol1 = l1act && (t + 1 < T_STEPS);
        float u = 0.0f;
        if (dol1) {
            const float xv = x[b * T_STEPS + (t + 1)];
            u = wi1 * xv + b1;
            #pragma unroll
            for (int k = 0; k < H1; ++k) u += w1[k] * h1s[cur][k];
        }

        if (jact) h2s[nxt][j]  = hn;
        if (dol1) h1s[nxt][li] = fast_tanh(u);
        __syncthreads();
        cur = nxt;
    }

    // ---- epilogue: out[b] = relu(W3 · h2_last + b3) ----
    if (tid == 0) {
        float s = b3[0];
        #pragma unroll
        for (int k = 0; k < H2; ++k) s += W3[k] * h2s[cur][k];
        out[b] = fmaxf(s, 0.0f);
    }
}

extern "C" void kernel_launch(void* const* d_in, const int* in_sizes, int n_in,
                              void* d_out, int out_size, void* d_ws, size_t ws_size,
                              hipStream_t stream) {
    const float* x    = (const float*)d_in[0];
    const float* Wih1 = (const float*)d_in[1];
    const float* Whh1 = (const float*)d_in[2];
    const float* bih1 = (const float*)d_in[3];
    const float* bhh1 = (const float*)d_in[4];
    const float* Wih2 = (const float*)d_in[5];
    const float* Whh2 = (const float*)d_in[6];
    const float* bih2 = (const float*)d_in[7];
    const float* bhh2 = (const float*)d_in[8];
    const float* W3   = (const float*)d_in[9];
    const float* b3   = (const float*)d_in[10];
    float* out = (float*)d_out;

    const int B = in_sizes[0] / T_STEPS;   // 4096
    rnn_fused<<<B, 128, 0, stream>>>(x, Wih1, Whh1, bih1, bhh1,
                                     Wih2, Whh2, bih2, bhh2, W3, b3, out);
}